// Round 6
// baseline (387.982 us; speedup 1.0000x reference)
//
#include <hip/hip_runtime.h>
#include <stdint.h>

// ---------------- problem constants ----------------
#define BATCH 16
#define NCLS 80
#define NPOS 21824            // 16384+4096+1024+256+64
#define POOLN 3320            // 1000+1000+1000+256+64
#define MAXDET 100

// superset segment capacities (multiples of 8)
#define CAP0 4096
#define CAP1 2432
#define CAP2 1024
#define CAP34 320
#define SEG1 (CAP0)                    // 4096
#define SEG2 (CAP0 + CAP1)             // 6528
#define SEG3 (CAP0 + CAP1 + CAP2)      // 7552
#define CAPTOT (SEG3 + CAP34)          // 7872

#define DEC_BPI 341                    // 21824/64 anchors-per-block blocks per image
#define RANK_BPI 16                    // 16 x 512 mykeys = 8192 >= CAPTOT

__device__ const int d_lvl_off[5] = {0, 16384, 20480, 21504, 21760};
__device__ const int d_lvl_hw[5]  = {16384, 4096, 1024, 256, 64};

struct Ptrs { const float* p[20]; };

__device__ __forceinline__ void map_lvl(int r, int& level, int& hw) {
  if      (r < 16384) { level = 0; hw = r; }
  else if (r < 20480) { level = 1; hw = r - 16384; }
  else if (r < 21504) { level = 2; hw = r - 20480; }
  else if (r < 21760) { level = 3; hw = r - 21504; }
  else                { level = 4; hw = r - 21760; }
}

// key = (~score_bits)<<32 | (level<<20) | hw; ascending == (score desc, level asc, idx asc).
// Unique per image; ~0ULL is a strictly-greater sentinel (score>0 -> hi word <= 0xC37FFFFF).

// ---------------- kernel 1: decode (4 lanes per anchor, register-only) ----------------
// Lane group {4a..4a+3}: part p owns classes [20p,20p+20) = 5 float4 loads issued
// back-to-back (one latency). Local argmax in ascending class order (strict '>') then
// shfl_xor combine preferring (greater) or (equal && lower class) -> exact first-occurrence
// argmax. Math identical to the proven R1/R4 decode. Also scatters deterministic
// level-3/4 keys into gbuf and zeroes gcnt for the histgather pass.
__global__ __launch_bounds__(256) void decode_kernel(Ptrs args, uint4* __restrict__ dec,
                                                     unsigned long long* __restrict__ gbuf,
                                                     int* __restrict__ gcnt) {
  int b  = blockIdx.x / DEC_BPI;
  int bb = blockIdx.x - b * DEC_BPI;
  int t = threadIdx.x;
  if (bb == 0 && t < 3) gcnt[b * 3 + t] = 0;

  int flat0 = bb * 64;                      // level boundaries are all multiples of 64
  int level, hw0;
  map_lvl(flat0, level, hw0);
  int HW = d_lvl_hw[level];
  int aoff = t >> 2, part = t & 3;
  int hw = hw0 + aoff;
  long abase = (long)b * HW + hw;

  const float* cls = args.p[level * 4 + 0];
  const float* reg = args.p[level * 4 + 1];
  const float* ctr = args.p[level * 4 + 2];
  const float* pos = args.p[level * 4 + 3];

  const float4* c4 = (const float4*)(cls + abase * NCLS) + part * 5;
  float4 v0 = c4[0], v1 = c4[1], v2 = c4[2], v3 = c4[3], v4 = c4[4];

  float m = -1e30f; int am = 0;
  int cb = part * 20;
#define CHK(val, j) if ((val) > m) { m = (val); am = cb + (j); }
  CHK(v0.x, 0)  CHK(v0.y, 1)  CHK(v0.z, 2)  CHK(v0.w, 3)
  CHK(v1.x, 4)  CHK(v1.y, 5)  CHK(v1.z, 6)  CHK(v1.w, 7)
  CHK(v2.x, 8)  CHK(v2.y, 9)  CHK(v2.z, 10) CHK(v2.w, 11)
  CHK(v3.x, 12) CHK(v3.y, 13) CHK(v3.z, 14) CHK(v3.w, 15)
  CHK(v4.x, 16) CHK(v4.y, 17) CHK(v4.z, 18) CHK(v4.w, 19)
#undef CHK
#pragma unroll
  for (int d = 1; d <= 2; d <<= 1) {
    float om = __shfl_xor(m, d, 64);
    int   oa = __shfl_xor(am, d, 64);
    if (om > m || (om == m && oa < am)) { m = om; am = oa; }
  }

  if (part == 0) {
    float4 rg = *(const float4*)(reg + abase * 4);
    float  ct = ctr[abase];
    float2 ps = ((const float2*)pos)[abase];

    float e0 = expf(rg.x), e1 = expf(rg.y), e2 = expf(rg.z), e3 = expf(rg.w);
    int x1 = (int)(ps.x - e0);   // C truncation == .astype(int32)
    int y1 = (int)(ps.y - e1);
    int x2 = (int)(ps.x + e2);
    int y2 = (int)(ps.y + e3);
    x1 = max(x1, 0); y1 = max(y1, 0);
    x2 = min(x2, 1023); y2 = min(y2, 1023);

    float sigm = 1.0f / (1.0f + expf(-m));
    float sigc = 1.0f / (1.0f + expf(-ct));
    float score = sqrtf(sigm * sigc);

    uint4 e;
    e.x = __float_as_uint(score);
    e.y = (unsigned)am;
    e.z = (unsigned)(x1 & 0xFFFF) | ((unsigned)y1 << 16);
    e.w = (unsigned)(x2 & 0xFFFF) | ((unsigned)y2 << 16);
    dec[b * NPOS + flat0 + aoff] = e;

    if (level >= 3) {    // deterministic slots for complete levels 3/4
      unsigned nsb = ~e.x;
      unsigned long long key =
          ((unsigned long long)nsb << 32) | (unsigned)((level << 20) | hw);
      gbuf[(size_t)b * CAPTOT + SEG3 + ((level == 3) ? hw : 256 + hw)] = key;
    }
  }
}

// ---------------- kernel 2: fused hist cutoff + superset scatter ----------------
// digit = (~score_bits) >> 19 is a 13-bit key PREFIX -> {digit <= B} is downward-closed.
// Parallel scan (shfl) replaces R5's tid0 serial 290-step walk. Then ballot-scatter of
// the superset into the single global gbuf layout (one atomic counter per img,level).
__global__ __launch_bounds__(256) void histgather_kernel(const uint4* __restrict__ dec,
                                                         unsigned long long* __restrict__ gbuf,
                                                         int* __restrict__ gcnt) {
  __shared__ unsigned hist[8192];
  __shared__ unsigned wpart[4];
  __shared__ int shB;
  int img = blockIdx.x / 3, level = blockIdx.x % 3;
  int N = d_lvl_hw[level];                       // 16384/4096/1024, all multiples of 256
  const uint4* base = dec + img * NPOS + d_lvl_off[level];
  int tid = threadIdx.x, lane = tid & 63, wv = tid >> 6;

  for (int i = tid; i < 8192; i += 256) hist[i] = 0;
  __syncthreads();
  for (int i = tid; i < N; i += 256)
    atomicAdd(&hist[(~base[i].x) >> 19], 1u);
  __syncthreads();

  unsigned s = 0;
#pragma unroll 8
  for (int k = 0; k < 32; ++k) s += hist[32 * tid + k];
  unsigned incl = s;
  for (int d = 1; d < 64; d <<= 1) {
    unsigned v = __shfl_up(incl, d, 64);
    if (lane >= d) incl += v;
  }
  if (lane == 63) wpart[wv] = incl;
  __syncthreads();
  unsigned woff = 0;
  for (int w = 0; w < wv; ++w) woff += wpart[w];
  unsigned excl = woff + incl - s;
  if (excl < 1000u && excl + s >= 1000u) {       // unique crossing thread (N >= 1000)
    unsigned cum = excl; int B = 8191;
    for (int k = 0; k < 32; ++k) {
      cum += hist[32 * tid + k];
      if (cum >= 1000u) { B = 32 * tid + k; break; }
    }
    shB = B;
  }
  __syncthreads();
  int B = shB;
  int cap   = (level == 0) ? CAP0 : (level == 1) ? CAP1 : CAP2;
  int sbase = (level == 0) ? 0    : (level == 1) ? SEG1 : SEG2;
  unsigned long long* gb = gbuf + (size_t)img * CAPTOT;

  for (int i = tid; i < N; i += 256) {           // uniform trips -> ballot safe
    unsigned nsb = ~base[i].x;
    bool sel = (int)(nsb >> 19) <= B;
    unsigned long long msk = __ballot(sel);
    if (msk) {
      int nsel = __popcll(msk);
      int bas = 0;
      if (lane == 0) bas = atomicAdd(&gcnt[img * 3 + level], nsel);
      bas = __shfl(bas, 0, 64);
      if (sel) {
        int p = bas + __popcll(msk & ((1ULL << lane) - 1ULL));
        unsigned long long key =
            ((unsigned long long)nsb << 32) | (unsigned)((level << 20) | i);
        if (p < cap) gb[sbase + p] = key;
      }
    }
  }
}

// ---------------- kernel 3: exact rank -> sorted pool (register-tiled, R=2) ----
// Exactness lemma unchanged from R4/R5 (absmax 0.0): pos(x) = sum_l min(n_l,1000) + n_34;
// level<=2 selected iff own-level n < 1000. Each lane ranks 2 keys so the broadcast
// comparand stream is amortized over 512 mykeys/block; LDS fill loads only live counts.
__global__ __launch_bounds__(256) void rank_kernel(const unsigned long long* __restrict__ gbuf,
                                                   const int* __restrict__ gcnt,
                                                   unsigned long long* __restrict__ pool) {
  __shared__ __align__(16) unsigned long long lk[CAPTOT];
  int img = blockIdx.x >> 4, bl = blockIdx.x & 15;
  int tid = threadIdx.x;
  const unsigned long long* gb = gbuf + (size_t)img * CAPTOT;

  int c0 = min(gcnt[img * 3 + 0], CAP0);
  int c1 = min(gcnt[img * 3 + 1], CAP1);
  int c2 = min(gcnt[img * 3 + 2], CAP2);
  int c0p = (c0 + 7) & ~7, c1p = (c1 + 7) & ~7, c2p = (c2 + 7) & ~7;

  for (int i = tid; i < c0p / 2; i += 256)
    ((ulonglong2*)lk)[i] = ((const ulonglong2*)gb)[i];
  for (int i = tid; i < c1p / 2; i += 256)
    ((ulonglong2*)(lk + SEG1))[i] = ((const ulonglong2*)(gb + SEG1))[i];
  for (int i = tid; i < c2p / 2; i += 256)
    ((ulonglong2*)(lk + SEG2))[i] = ((const ulonglong2*)(gb + SEG2))[i];
  for (int i = tid; i < CAP34 / 2; i += 256)
    ((ulonglong2*)(lk + SEG3))[i] = ((const ulonglong2*)(gb + SEG3))[i];
  __syncthreads();
  // overwrite the rounded-up tail (loaded garbage) with strictly-greater sentinels
  if (tid < 8)       { int j = c0 + tid;        if (j < c0p) lk[j] = ~0ULL; }
  else if (tid < 16) { int j = c1 + (tid - 8);  if (j < c1p) lk[SEG1 + j] = ~0ULL; }
  else if (tid < 24) { int j = c2 + (tid - 16); if (j < c2p) lk[SEG2 + j] = ~0ULL; }
  __syncthreads();

  // classify my 2 slots
  int e0 = bl * 512 + tid, e1 = e0 + 256;
  int seg[2], pos[2] = {0, 0};
  bool val[2], sel[2] = {false, false};
  unsigned long long mk[2];
  int ee[2] = {e0, e1};
#pragma unroll
  for (int r = 0; r < 2; ++r) {
    int e = ee[r];
    int sg, slot;
    if      (e < SEG1)   { sg = 0; slot = e; }
    else if (e < SEG2)   { sg = 1; slot = e - SEG1; }
    else if (e < SEG3)   { sg = 2; slot = e - SEG2; }
    else if (e < CAPTOT) { sg = 3; slot = e - SEG3; }
    else                 { sg = -1; slot = 0; }
    bool v = (sg == 0) ? (slot < c0) : (sg == 1) ? (slot < c1)
           : (sg == 2) ? (slot < c2) : (sg == 3);   // seg3 slots always < 320
    seg[r] = sg; val[r] = v;
    mk[r] = v ? lk[e] : ~0ULL;
  }

#define SEGLOOP(base_, lim_, sidx)                                               \
  { int n0 = 0, n1 = 0;                                                          \
    for (int j = 0; j < (lim_); j += 4) {                                        \
      unsigned long long a0 = lk[(base_) + j + 0], a1 = lk[(base_) + j + 1];     \
      unsigned long long a2 = lk[(base_) + j + 2], a3 = lk[(base_) + j + 3];     \
      n0 += (int)(a0 < mk[0]) + (int)(a1 < mk[0]) +                              \
            (int)(a2 < mk[0]) + (int)(a3 < mk[0]);                               \
      n1 += (int)(a0 < mk[1]) + (int)(a1 < mk[1]) +                              \
            (int)(a2 < mk[1]) + (int)(a3 < mk[1]);                               \
    }                                                                            \
    pos[0] += min(n0, 1000); pos[1] += min(n1, 1000);                            \
    if (seg[0] == (sidx)) sel[0] = n0 < 1000;                                    \
    if (seg[1] == (sidx)) sel[1] = n1 < 1000;                                    \
  }
  SEGLOOP(0,    c0p,   0)
  SEGLOOP(SEG1, c1p,   1)
  SEGLOOP(SEG2, c2p,   2)
  SEGLOOP(SEG3, CAP34, 3)
#undef SEGLOOP

#pragma unroll
  for (int r = 0; r < 2; ++r)
    if (val[r] && sel[r]) pool[img * POOLN + pos[r]] = mk[r];
}

// ---------------- kernel 4: per-image greedy NMS + output (bit-identical, proven) --
__global__ __launch_bounds__(64) void nms_kernel(const uint4* __restrict__ dec,
                                                 const unsigned long long* __restrict__ pool,
                                                 float* __restrict__ out) {
  __shared__ float          s_score[POOLN];
  __shared__ unsigned short s_cls[POOLN];
  __shared__ uint2          s_box[POOLN];
  int img = blockIdx.x;
  int lane = threadIdx.x;

  for (int r = lane; r < POOLN; r += 64) {
    unsigned long long key = pool[img * POOLN + r];
    unsigned low = (unsigned)key;
    int level = (low >> 20) & 7;
    int idx = low & 0xFFFFF;
    uint4 e = dec[img * NPOS + d_lvl_off[level] + idx];
    s_score[r] = __uint_as_float(e.x);
    s_cls[r]   = (unsigned short)e.y;
    s_box[r]   = make_uint2(e.z, e.w);
  }
  __syncthreads();

  float* out_s = out + img * MAXDET;
  float* out_c = out + BATCH * MAXDET + img * MAXDET;
  float* out_b = out + 2 * BATCH * MAXDET + img * MAXDET * 4;

  int kx1[2], ky1[2], kx2[2], ky2[2], kar[2];
  int k = 0;

  for (int i = 0; i < POOLN; ++i) {
    float sc = s_score[i];
    if (!(sc > 0.01f)) break;   // sorted desc: all remaining invalid too
    uint2 bx = s_box[i];
    int x1 = bx.x & 0xFFFF, y1 = bx.x >> 16;
    int x2 = bx.y & 0xFFFF, y2 = bx.y >> 16;
    int area = (x2 - x1) * (y2 - y1);

    bool sup = false;
#pragma unroll
    for (int sidx = 0; sidx < 2; ++sidx) {
      int slot = (sidx << 6) | lane;
      if (slot < k) {
        int xx1 = max(x1, kx1[sidx]), yy1 = max(y1, ky1[sidx]);
        int xx2 = min(x2, kx2[sidx]), yy2 = min(y2, ky2[sidx]);
        int iw = max(xx2 - xx1, 0), ih = max(yy2 - yy1, 0);
        int inter = iw * ih;
        float iou = (float)inter / (float)(area + kar[sidx] - inter);
        sup = sup || (iou > 0.6f);
      }
    }
    if (!__any(sup)) {
      if ((k & 63) == lane) {
        int hi = k >> 6;
        kx1[hi] = x1; ky1[hi] = y1; kx2[hi] = x2; ky2[hi] = y2; kar[hi] = area;
      }
      if (lane == 0) {
        out_s[k] = sc;
        out_c[k] = (float)(int)s_cls[i];
        out_b[k * 4 + 0] = (float)x1;
        out_b[k * 4 + 1] = (float)y1;
        out_b[k * 4 + 2] = (float)x2;
        out_b[k * 4 + 3] = (float)y2;
      }
      ++k;
      if (k == MAXDET) break;
    }
  }

  for (int s = k + lane; s < MAXDET; s += 64) {
    out_s[s] = -1.0f;
    out_c[s] = -1.0f;
    out_b[s * 4 + 0] = -1.0f;
    out_b[s * 4 + 1] = -1.0f;
    out_b[s * 4 + 2] = -1.0f;
    out_b[s * 4 + 3] = -1.0f;
  }
}

// ---------------- launcher ----------------
extern "C" void kernel_launch(void* const* d_in, const int* in_sizes, int n_in,
                              void* d_out, int out_size, void* d_ws, size_t ws_size,
                              hipStream_t stream) {
  Ptrs args;
  for (int i = 0; i < 20; ++i) args.p[i] = (const float*)d_in[i];

  char* ws = (char*)d_ws;
  uint4* dec = (uint4*)ws;                              // 5,586,944 B
  ws += (size_t)BATCH * NPOS * 16;
  unsigned long long* pool = (unsigned long long*)ws;   // 424,960 B
  ws += (size_t)BATCH * POOLN * 8;
  unsigned long long* gbuf = (unsigned long long*)ws;   // 1,007,616 B (16B-aligned)
  ws += (size_t)BATCH * CAPTOT * 8;
  int* gcnt = (int*)ws;                                 // 192 B
  float* out = (float*)d_out;

  decode_kernel<<<BATCH * DEC_BPI, 256, 0, stream>>>(args, dec, gbuf, gcnt);
  histgather_kernel<<<BATCH * 3, 256, 0, stream>>>(dec, gbuf, gcnt);
  rank_kernel<<<BATCH * RANK_BPI, 256, 0, stream>>>(gbuf, gcnt, pool);
  nms_kernel<<<BATCH, 64, 0, stream>>>(dec, pool, out);
}